// Round 5
// baseline (430.087 us; speedup 1.0000x reference)
//
#include <hip/hip_runtime.h>

// Depthwise causal conv1d: x (4, 2048, 8192) f32, weight (2048,1,16) f32, bias (2048) f32.
// out[n,c,l] = sum_{k=0..15} x[n,c,l+k-15] * w[c,k] + bias[c]   (x index <0 -> 0)
// Memory-bound: ~512 MiB unique traffic -> ~85us floor @ 6.29 TB/s (m13 float4-copy).
//
// R2: big per-thread arrays -> scratch spill (VGPR=32, WRITE 3x).      858 us
// R3: 1xfloat4/thread, 5x overlapping global loads, NT stores.        ~160 us
// R4: LDS tile 1024, plain stores.                                    ~130 us
// R5: TILE=4096 (4 float4/thread): 4-deep independent loads per wave,
//     per-block overhead (weights/halo/barrier/churn) amortized 4x.

#define DIMC 2048
#define LEN 8192
#define KW 16
#define TPB 256
#define TILE 4096          // elements per block = 256 threads x 4 float4
#define F4PT 4             // float4s per thread

typedef float vfloat4 __attribute__((ext_vector_type(4)));

__global__ __launch_bounds__(TPB) void causal_conv1d_kernel(
    const float* __restrict__ x,
    const float* __restrict__ w,
    const float* __restrict__ bias,
    float* __restrict__ out)
{
    // 2 tiles per row, 8192 rows -> 16384 blocks.
    const int bid  = blockIdx.x;
    const int row  = bid >> 1;                 // n*DIMC + c
    const int tile = (bid & 1) * TILE;         // start element within row
    const int c    = row & (DIMC - 1);
    const float* __restrict__ xr = x + (size_t)row * LEN;

    const int t = threadIdx.x;

    // lds[0..15] = halo x[tile-16 .. tile-1] (zeros at row start)
    // lds[16..16+TILE) = x[tile .. tile+TILE)
    __shared__ float lds[TILE + 16];

    // ---- stage: 4 independent coalesced b128 loads per thread (deep MLP) ----
    vfloat4 mv[F4PT];
    #pragma unroll
    for (int q = 0; q < F4PT; ++q)
        mv[q] = *reinterpret_cast<const vfloat4*>(xr + tile + q * 1024 + t * 4);
    #pragma unroll
    for (int q = 0; q < F4PT; ++q)
        *reinterpret_cast<vfloat4*>(&lds[16 + q * 1024 + t * 4]) = mv[q];

    // ---- halo (4 threads) ----
    if (t < 4) {
        vfloat4 hv = {0.0f, 0.0f, 0.0f, 0.0f};
        if (tile != 0)
            hv = *reinterpret_cast<const vfloat4*>(xr + tile - 16 + t * 4);
        *reinterpret_cast<vfloat4*>(&lds[t * 4]) = hv;
    }

    // ---- weights + bias (uniform per block -> broadcast) ----
    float wv[KW];
    {
        const vfloat4* w4 = reinterpret_cast<const vfloat4*>(w + (size_t)c * KW);
        #pragma unroll
        for (int i = 0; i < KW / 4; ++i) {
            vfloat4 v = w4[i];
            #pragma unroll
            for (int m = 0; m < 4; ++m) wv[4*i + m] = v[m];
        }
    }
    const float bv = bias[c];

    __syncthreads();

    // ---- 4 output float4s per thread ----
    #pragma unroll
    for (int q = 0; q < F4PT; ++q) {
        const int base = q * 1024 + t * 4;     // element offset within tile

        // win[u] = x[tile + base - 16 + u] = lds[base + u]; 5x conflict-free b128
        float win[20];
        #pragma unroll
        for (int j = 0; j < 5; ++j) {
            vfloat4 v = *reinterpret_cast<const vfloat4*>(&lds[base + j * 4]);
            #pragma unroll
            for (int m = 0; m < 4; ++m) win[4*j + m] = v[m];
        }

        vfloat4 acc;
        #pragma unroll
        for (int i = 0; i < 4; ++i) {
            float a = bv;
            #pragma unroll
            for (int k = 0; k < KW; ++k)
                a = fmaf(win[i + k + 1], wv[k], a);
            acc[i] = a;
        }

        *reinterpret_cast<vfloat4*>(out + (size_t)row * LEN + tile + base) = acc;
    }
}

extern "C" void kernel_launch(void* const* d_in, const int* in_sizes, int n_in,
                              void* d_out, int out_size, void* d_ws, size_t ws_size,
                              hipStream_t stream) {
    const float* x    = (const float*)d_in[0];
    const float* w    = (const float*)d_in[1];
    const float* bias = (const float*)d_in[2];
    float* out = (float*)d_out;

    const int blocks = (4 * DIMC * LEN) / TILE;   // 16384
    causal_conv1d_kernel<<<blocks, TPB, 0, stream>>>(x, w, bias, out);
}